// Round 4
// baseline (894.116 us; speedup 1.0000x reference)
//
#include <hip/hip_runtime.h>
#include <hip/hip_bf16.h>

#define VOCAB 50257
#define EMB 256
#define HID 256
#define BB 128
#define SS 2048

typedef __attribute__((ext_vector_type(8))) short short8;
typedef __attribute__((ext_vector_type(4))) float f32x4;

__device__ inline unsigned short f2bf(float f) {
    unsigned int u = __float_as_uint(f);
    u += 0x7FFFu + ((u >> 16) & 1u);
    return (unsigned short)(u >> 16);
}
__device__ inline unsigned int pack2(float a, float b) {
    return (unsigned int)f2bf(a) | ((unsigned int)f2bf(b) << 16);
}
// tanh(x) = 1 - 2/(exp(2x)+1); saturates correctly for |x| large, no clamp.
__device__ inline float fast_tanh(float x) {
    float t = __expf(2.f * x);
    return 1.f - 2.f * __builtin_amdgcn_rcpf(t + 1.f);
}

// ---------------------------------------------------------------------------
// K1: qb[b][h] = W1_b[h] + W2_b[h] + sum_k h0[b][k]*W2[h][k]   (blocks 0..127)
//     W1 fp32 -> bf16 [h][k]                                    (blocks 128..191)
// ---------------------------------------------------------------------------
__global__ __launch_bounds__(256) void k_prep(
    const float* __restrict__ hidden, const float* __restrict__ W2,
    const float* __restrict__ W1bias, const float* __restrict__ W2bias,
    const float* __restrict__ W1, unsigned short* __restrict__ W1bf,
    float* __restrict__ qb)
{
    const int bid = blockIdx.x, tid = threadIdx.x;
    if (bid < BB) {
        __shared__ float h0s[HID];
        h0s[tid] = hidden[bid * HID + tid];
        __syncthreads();
        const float4* w2r = (const float4*)(W2 + (size_t)tid * HID);
        float acc = W1bias[tid] + W2bias[tid];
        #pragma unroll 4
        for (int k4 = 0; k4 < HID / 4; ++k4) {
            float4 w = w2r[k4];
            acc += w.x * h0s[k4*4] + w.y * h0s[k4*4+1] + w.z * h0s[k4*4+2] + w.w * h0s[k4*4+3];
        }
        qb[bid * HID + tid] = acc;
    } else {
        int idx = (bid - BB) * 256 + tid;        // 16384 float4s total
        float4 v = ((const float4*)W1)[idx];
        ushort4 o;
        o.x = f2bf(v.x); o.y = f2bf(v.y); o.z = f2bf(v.z); o.w = f2bf(v.w);
        ((ushort4*)W1bf)[idx] = o;
    }
}

// ---------------------------------------------------------------------------
// K2: e2[s][b] = V_b + sum_h V[h] * tanh( enc[s,b,:]@W1[h,:] + qb[b][h] )
// enc viewed as [S*B, 256] row-major (r = s*128+b). Block = 64 rows x 256 h.
// 256 thr / 4 waves (1x4). Wave tile 64x64: Mrep=4, Nrep=4. BK=64, 4 kt.
// A+B register-prefetched (T14): loads for kt+1 issued during compute of kt.
// ---------------------------------------------------------------------------
__global__ __launch_bounds__(256) void k_escore(
    const float* __restrict__ enc, const unsigned short* __restrict__ W1bf,
    const float* __restrict__ qb, const float* __restrict__ Vw,
    const float* __restrict__ Vb, float* __restrict__ e2)
{
    __shared__ __align__(16) char As[64 * 128];    // 64 rows x 64 k bf16, swizzled
    __shared__ __align__(16) char Bs[256 * 128];   // 256 cols x 64 k bf16, swizzled
    __shared__ float esum[64];

    const int tid = threadIdx.x;
    const int lane = tid & 63, wn = tid >> 6;      // 4 waves, all n-split
    const int lg = lane >> 4, li = lane & 15;
    const int blk = blockIdx.x;
    const size_t row0 = (size_t)blk * 64;          // global flat row base

    if (tid < 64) esum[tid] = 0.f;

    f32x4 acc[4][4];
    #pragma unroll
    for (int m = 0; m < 4; ++m)
        #pragma unroll
        for (int n = 0; n < 4; ++n)
            acc[m][n] = (f32x4){0.f, 0.f, 0.f, 0.f};

    float4 ar[4];   // A prefetch: 64x64 fp32 tile = 1024 float4 slots / 256 thr
    uint4  br[8];   // B prefetch: 256x64 bf16 tile = 2048 uint4 slots / 256 thr

    auto load_tile = [&](int kt) {
        #pragma unroll
        for (int i = 0; i < 4; ++i) {
            const int slot = tid + 256 * i;
            const int row = slot >> 4, k16 = slot & 15;   // 16 float4 per row
            ar[i] = *(const float4*)(enc + (row0 + row) * HID + kt * 64 + k16 * 4);
        }
        #pragma unroll
        for (int i = 0; i < 8; ++i) {
            const int slot = tid + 256 * i;
            const int col = slot >> 3, k8 = slot & 7;     // 8 uint4 per col
            br[i] = *((const uint4*)(W1bf + (size_t)col * HID + kt * 64) + k8);
        }
    };
    auto write_tile = [&]() {
        #pragma unroll
        for (int i = 0; i < 4; ++i) {
            const int slot = tid + 256 * i;
            const int row = slot >> 4, k16 = slot & 15;
            *(uint2*)(As + row * 128 + ((k16 * 8) ^ ((row & 7) << 4))) =
                make_uint2(pack2(ar[i].x, ar[i].y), pack2(ar[i].z, ar[i].w));
        }
        #pragma unroll
        for (int i = 0; i < 8; ++i) {
            const int slot = tid + 256 * i;
            const int col = slot >> 3, k8 = slot & 7;
            *(uint4*)(Bs + col * 128 + ((k8 * 16) ^ ((col & 7) << 4))) = br[i];
        }
    };
    auto compute_tile = [&]() {
        #pragma unroll
        for (int ks = 0; ks < 2; ++ks) {
            short8 a[4];
            #pragma unroll
            for (int m = 0; m < 4; ++m) {
                const int r = m * 16 + li;
                a[m] = *(const short8*)(As + r * 128 + ((ks * 64 + lg * 16) ^ ((r & 7) << 4)));
            }
            #pragma unroll
            for (int n = 0; n < 4; ++n) {
                const int c = wn * 64 + n * 16 + li;
                short8 b = *(const short8*)(Bs + c * 128 + ((ks * 64 + lg * 16) ^ ((c & 7) << 4)));
                #pragma unroll
                for (int m = 0; m < 4; ++m)
                    acc[m][n] = __builtin_amdgcn_mfma_f32_16x16x32_bf16(a[m], b, acc[m][n], 0, 0, 0);
            }
        }
    };

    load_tile(0);
    #pragma unroll
    for (int kt = 0; kt < 4; ++kt) {
        __syncthreads();
        write_tile();
        __syncthreads();
        if (kt < 3) load_tile(kt + 1);   // overlaps with compute below
        compute_tile();
    }

    // epilogue: p(row) = sum_h V[h]*tanh(acc + qb[b][h]); 16-lane reduce
    float vw[4];
    #pragma unroll
    for (int n = 0; n < 4; ++n) vw[n] = Vw[wn * 64 + n * 16 + li];

    const int bbase = (blk & 1) * 64;    // b = bbase + lrow; s = blk >> 1
    #pragma unroll
    for (int m = 0; m < 4; ++m) {
        #pragma unroll
        for (int r = 0; r < 4; ++r) {
            const int lrow = m * 16 + lg * 4 + r;
            const float* qbrow = qb + (size_t)(bbase + lrow) * HID;
            float p = 0.f;
            #pragma unroll
            for (int n = 0; n < 4; ++n) {
                const int h = wn * 64 + n * 16 + li;
                p += vw[n] * fast_tanh(acc[m][n][r] + qbrow[h]);
            }
            p += __shfl_xor(p, 1); p += __shfl_xor(p, 2);
            p += __shfl_xor(p, 4); p += __shfl_xor(p, 8);
            if (li == 0) atomicAdd(&esum[lrow], p);
        }
    }
    __syncthreads();
    if (tid < 64) {
        const int s = blk >> 1, b = bbase + tid;
        e2[(size_t)s * BB + b] = esum[tid] + Vb[0];
    }
}

// ---------------------------------------------------------------------------
// K3: softmax over s per b; e2 is [s][b]; writes attw [b][s] into d_out
// ---------------------------------------------------------------------------
__global__ __launch_bounds__(256) void k_softmax(
    const float* __restrict__ e2, float* __restrict__ attw)
{
    __shared__ float redm[4];
    __shared__ float reds[4];
    const int b = blockIdx.x, tid = threadIdx.x;
    float v[8];
    float m = -1e30f;
    #pragma unroll
    for (int i = 0; i < 8; ++i) {
        v[i] = e2[(size_t)(tid + i * 256) * BB + b];
        m = fmaxf(m, v[i]);
    }
    #pragma unroll
    for (int off = 1; off < 64; off <<= 1) m = fmaxf(m, __shfl_xor(m, off));
    if ((tid & 63) == 0) redm[tid >> 6] = m;
    __syncthreads();
    m = fmaxf(fmaxf(redm[0], redm[1]), fmaxf(redm[2], redm[3]));
    float sum = 0.f;
    #pragma unroll
    for (int i = 0; i < 8; ++i) { v[i] = __expf(v[i] - m); sum += v[i]; }
    #pragma unroll
    for (int off = 1; off < 64; off <<= 1) sum += __shfl_xor(sum, off);
    if ((tid & 63) == 0) reds[tid >> 6] = sum;
    __syncthreads();
    const float inv = 1.f / (reds[0] + reds[1] + reds[2] + reds[3]);
    float* aw = attw + (size_t)b * SS;
    #pragma unroll
    for (int i = 0; i < 8; ++i) aw[tid + i * 256] = v[i] * inv;
}

// ---------------------------------------------------------------------------
// K4: ctx[b][h] += sum_{s in chunk} attw[b][s] * enc[s][b][h]
// grid = 128 b * 16 chunks of 128 s. float4 loads, 4-way s-parallel, unroll 8.
// ---------------------------------------------------------------------------
__global__ __launch_bounds__(256) void k_ctx(
    const float* __restrict__ enc, const float* __restrict__ attw,
    float* __restrict__ ctx)
{
    __shared__ float aws[128];
    __shared__ f32x4 red[256];
    const int b = blockIdx.x >> 4, chunk = blockIdx.x & 15, tid = threadIdx.x;
    const int s0 = chunk * 128;
    const int hq = tid & 63, sg = tid >> 6;
    if (tid < 128) aws[tid] = attw[(size_t)b * SS + s0 + tid];
    __syncthreads();
    const f32x4* base = (const f32x4*)enc + ((size_t)s0 * BB + b) * 64 + hq;
    f32x4 acc = (f32x4){0.f, 0.f, 0.f, 0.f};
    #pragma unroll 8
    for (int i = 0; i < 32; ++i) {
        const int sl = sg + i * 4;
        f32x4 v = base[(size_t)sl * (BB * HID / 4)];
        acc += v * aws[sl];
    }
    red[tid] = acc;
    __syncthreads();
    if (tid < 64) {
        f32x4 r = red[tid] + red[tid + 64] + red[tid + 128] + red[tid + 192];
        #pragma unroll
        for (int j = 0; j < 4; ++j)
            atomicAdd(&ctx[b * HID + tid * 4 + j], r[j]);
    }
}

// ---------------------------------------------------------------------------
// K5: LSTM step (fp32 exact). One block per b. Also emits h_new in bf16.
// ---------------------------------------------------------------------------
__global__ __launch_bounds__(256) void k_lstm(
    const float* __restrict__ ctx, const int* __restrict__ x,
    const float* __restrict__ emb_table, const float* __restrict__ hidden,
    const float* __restrict__ cell,
    const float* __restrict__ W_ih, const float* __restrict__ W_hh,
    const float* __restrict__ b_ih, const float* __restrict__ b_hh,
    float* __restrict__ out_h, float* __restrict__ out_c,
    unsigned short* __restrict__ hbf)
{
    __shared__ float rin[768];     // [ctx | emb | h0]
    __shared__ float gates[1024];
    const int b = blockIdx.x, tid = threadIdx.x;
    rin[tid]       = ctx[b * HID + tid];
    rin[256 + tid] = emb_table[(size_t)x[b] * EMB + tid];
    rin[512 + tid] = hidden[b * HID + tid];
    __syncthreads();
    #pragma unroll
    for (int jj = 0; jj < 4; ++jj) {
        const int j = jj * 256 + tid;
        float acc = b_ih[j] + b_hh[j];
        const float4* wi = (const float4*)(W_ih + (size_t)j * 512);
        #pragma unroll 4
        for (int k4 = 0; k4 < 128; ++k4) {
            float4 w = wi[k4];
            acc += w.x*rin[k4*4] + w.y*rin[k4*4+1] + w.z*rin[k4*4+2] + w.w*rin[k4*4+3];
        }
        const float4* wh = (const float4*)(W_hh + (size_t)j * 256);
        #pragma unroll 4
        for (int k4 = 0; k4 < 64; ++k4) {
            float4 w = wh[k4];
            acc += w.x*rin[512+k4*4] + w.y*rin[512+k4*4+1] + w.z*rin[512+k4*4+2] + w.w*rin[512+k4*4+3];
        }
        gates[j] = acc;
    }
    __syncthreads();
    const float ig = gates[tid], fg = gates[256 + tid];
    const float gg = gates[512 + tid], og = gates[768 + tid];
    const float c0 = cell[b * HID + tid];
    const float si = 1.f / (1.f + __expf(-ig));
    const float sf = 1.f / (1.f + __expf(-fg));
    const float so = 1.f / (1.f + __expf(-og));
    const float cn = sf * c0 + si * tanhf(gg);
    const float hn = so * tanhf(cn);
    out_c[b * HID + tid] = cn;
    out_h[b * HID + tid] = hn;
    hbf[b * HID + tid] = f2bf(hn);
}

// ---------------------------------------------------------------------------
// K6: predictions[b][v] = h_new[b,:]@fc_w[v,:] + fc_b[v]
// Tile 128(b) x 128(v), 256 thr / 4 waves (2x2), BK=64, A+B reg-prefetch.
// A from hbf (bf16, L2-hot); B from fc_w fp32 (HBM).
// ---------------------------------------------------------------------------
__global__ __launch_bounds__(256) void k_fc(
    const unsigned short* __restrict__ hbf, const float* __restrict__ fcw,
    const float* __restrict__ fcb, float* __restrict__ pred)
{
    __shared__ __align__(16) char As[128 * 128];   // 128 rows x 64 k bf16, swizzled
    __shared__ __align__(16) char Bs[128 * 128];   // 128 cols x 64 k bf16, swizzled
    const int vbase = blockIdx.x * 128;
    const int tid = threadIdx.x;
    const int lane = tid & 63, wid = tid >> 6;
    const int wm = wid >> 1, wn = wid & 1;
    const int lg = lane >> 4, li = lane & 15;

    f32x4 acc[4][4];
    #pragma unroll
    for (int m = 0; m < 4; ++m)
        #pragma unroll
        for (int n = 0; n < 4; ++n)
            acc[m][n] = (f32x4){0.f, 0.f, 0.f, 0.f};

    uint4  arg[4];   // A: 128x64 bf16 = 1024 uint4 slots / 256 thr
    float4 brg[8];   // B: 128x64 fp32 = 2048 float4 slots / 256 thr

    auto load_tile = [&](int kt) {
        #pragma unroll
        for (int i = 0; i < 4; ++i) {
            const int slot = tid + 256 * i;
            const int row = slot >> 3, k8 = slot & 7;     // 8 uint4 per row
            arg[i] = *((const uint4*)(hbf + (size_t)row * HID + kt * 64) + k8);
        }
        #pragma unroll
        for (int i = 0; i < 8; ++i) {
            const int slot = tid + 256 * i;
            const int row = slot >> 4, k16 = slot & 15;   // 16 float4 per row
            const int v = min(vbase + row, VOCAB - 1);
            brg[i] = *(const float4*)(fcw + (size_t)v * HID + kt * 64 + k16 * 4);
        }
    };
    auto write_tile = [&]() {
        #pragma unroll
        for (int i = 0; i < 4; ++i) {
            const int slot = tid + 256 * i;
            const int row = slot >> 3, k8 = slot & 7;
            *(uint4*)(As + row * 128 + ((k8 * 16) ^ ((row & 7) << 4))) = arg[i];
        }
        #pragma unroll
        for (int i = 0; i < 8; ++i) {
            const int slot = tid + 256 * i;
            const int row = slot >> 4, k16 = slot & 15;
            *(uint2*)(Bs + row * 128 + ((k16 * 8) ^ ((row & 7) << 4))) =
                make_uint2(pack2(brg[i].x, brg[i].y), pack2(brg[i].z, brg[i].w));
        }
    };
    auto compute_tile = [&]() {
        #pragma unroll
        for (int ks = 0; ks < 2; ++ks) {
            short8 a[4];
            #pragma unroll
            for (int m = 0; m < 4; ++m) {
                const int r = wm * 64 + m * 16 + li;
                a[m] = *(const short8*)(As + r * 128 + ((ks * 64 + lg * 16) ^ ((r & 7) << 4)));
            }
            #pragma unroll
            for (int n = 0; n < 4; ++n) {
                const int c = wn * 64 + n * 16 + li;
                short8 b = *(const short8*)(Bs + c * 128 + ((ks * 64 + lg * 16) ^ ((c & 7) << 4)));
                #pragma unroll
                for (int m = 0; m < 4; ++m)
                    acc[m][n] = __builtin_amdgcn_mfma_f32_16x16x32_bf16(a[m], b, acc[m][n], 0, 0, 0);
            }
        }
    };

    load_tile(0);
    #pragma unroll
    for (int kt = 0; kt < 4; ++kt) {
        __syncthreads();
        write_tile();
        __syncthreads();
        if (kt < 3) load_tile(kt + 1);
        compute_tile();
    }

    #pragma unroll
    for (int m = 0; m < 4; ++m)
        #pragma unroll
        for (int r = 0; r < 4; ++r) {
            const int row = wm * 64 + m * 16 + lg * 4 + r;
            #pragma unroll
            for (int n = 0; n < 4; ++n) {
                const int col = vbase + wn * 64 + n * 16 + li;
                if (col < VOCAB)
                    pred[(size_t)row * VOCAB + col] = acc[m][n][r] + fcb[col];
            }
        }
}

// ---------------------------------------------------------------------------
extern "C" void kernel_launch(void* const* d_in, const int* in_sizes, int n_in,
                              void* d_out, int out_size, void* d_ws, size_t ws_size,
                              hipStream_t stream)
{
    const int*   x      = (const int*)  d_in[0];
    const float* enc    = (const float*)d_in[1];
    const float* hidden = (const float*)d_in[2];
    const float* cell   = (const float*)d_in[3];
    const float* emb    = (const float*)d_in[4];
    const float* W_ih   = (const float*)d_in[5];
    const float* W_hh   = (const float*)d_in[6];
    const float* b_ih   = (const float*)d_in[7];
    const float* b_hh   = (const float*)d_in[8];
    const float* fc_w   = (const float*)d_in[9];
    const float* fc_b   = (const float*)d_in[10];
    const float* W1_w   = (const float*)d_in[11];
    const float* W1_b   = (const float*)d_in[12];
    const float* W2_w   = (const float*)d_in[13];
    const float* W2_b   = (const float*)d_in[14];
    const float* V_w    = (const float*)d_in[15];
    const float* V_b    = (const float*)d_in[16];

    float* out   = (float*)d_out;
    float* pred  = out;                                   // [128][50257]
    float* out_h = out + (size_t)BB * VOCAB;              // [128][256]
    float* out_c = out_h + BB * HID;                      // [128][256]
    float* attw  = out_c + BB * HID;                      // [128][2048]

    char* ws = (char*)d_ws;
    unsigned short* W1bf = (unsigned short*)ws;           // 131072 B
    float* qb  = (float*)(ws + 131072);                   // 131072 B
    float* e2  = (float*)(ws + 262144);                   // 1 MiB  [s][b]
    float* ctx = (float*)(ws + 1310720);                  // 131072 B
    unsigned short* hbf = (unsigned short*)(ws + 1441792);// 65536 B

    k_prep   <<<dim3(192),               dim3(256), 0, stream>>>(hidden, W2_w, W1_b, W2_b, W1_w, W1bf, qb);
    k_escore <<<dim3(SS * 2),            dim3(256), 0, stream>>>(enc, W1bf, qb, V_w, V_b, e2);
    k_softmax<<<dim3(BB),                dim3(256), 0, stream>>>(e2, attw);
    hipMemsetAsync(ctx, 0, BB * HID * sizeof(float), stream);
    k_ctx    <<<dim3(BB * 16),           dim3(256), 0, stream>>>(enc, attw, ctx);
    k_lstm   <<<dim3(BB),                dim3(256), 0, stream>>>(ctx, x, emb, hidden, cell,
                                                                 W_ih, W_hh, b_ih, b_hh, out_h, out_c, hbf);
    k_fc     <<<dim3((VOCAB + 127)/128), dim3(256), 0, stream>>>(hbf, fc_w, fc_b, pred);
}

// Round 6
// 691.559 us; speedup vs baseline: 1.2929x; 1.2929x over previous
//
#include <hip/hip_runtime.h>
#include <hip/hip_bf16.h>

#define VOCAB 50257
#define EMB 256
#define HID 256
#define BB 128
#define SS 2048

typedef __attribute__((ext_vector_type(8))) short short8;
typedef __attribute__((ext_vector_type(4))) float f32x4;

__device__ inline unsigned short f2bf(float f) {
    unsigned int u = __float_as_uint(f);
    u += 0x7FFFu + ((u >> 16) & 1u);
    return (unsigned short)(u >> 16);
}
__device__ inline unsigned int pack2(float a, float b) {
    return (unsigned int)f2bf(a) | ((unsigned int)f2bf(b) << 16);
}
// tanh(x) = 1 - 2/(exp(2x)+1); saturates correctly for |x| large.
__device__ inline float fast_tanh(float x) {
    float t = __expf(2.f * x);
    return 1.f - 2.f * __builtin_amdgcn_rcpf(t + 1.f);
}
// async global->LDS 16B per lane; lds base must be wave-uniform (HW scatters +lane*16)
__device__ __forceinline__ void glds16(const void* g, void* l) {
    __builtin_amdgcn_global_load_lds(
        (__attribute__((address_space(1))) void*)g,
        (__attribute__((address_space(3))) void*)l, 16, 0, 0);
}

// ---------------------------------------------------------------------------
// K1: qb[b][h] = W1_b[h]+W2_b[h]+h0[b]@W2[h]  (blocks 0..127)
//     W1 fp32 -> bf16                          (blocks 128..191)
// ---------------------------------------------------------------------------
__global__ __launch_bounds__(256) void k_prep(
    const float* __restrict__ hidden, const float* __restrict__ W2,
    const float* __restrict__ W1bias, const float* __restrict__ W2bias,
    const float* __restrict__ W1, unsigned short* __restrict__ W1bf,
    float* __restrict__ qb)
{
    const int bid = blockIdx.x, tid = threadIdx.x;
    if (bid < BB) {
        __shared__ float h0s[HID];
        h0s[tid] = hidden[bid * HID + tid];
        __syncthreads();
        const float4* w2r = (const float4*)(W2 + (size_t)tid * HID);
        float acc = W1bias[tid] + W2bias[tid];
        #pragma unroll 4
        for (int k4 = 0; k4 < HID / 4; ++k4) {
            float4 w = w2r[k4];
            acc += w.x * h0s[k4*4] + w.y * h0s[k4*4+1] + w.z * h0s[k4*4+2] + w.w * h0s[k4*4+3];
        }
        qb[bid * HID + tid] = acc;
    } else {
        int idx = (bid - BB) * 256 + tid;
        float4 v = ((const float4*)W1)[idx];
        ushort4 o;
        o.x = f2bf(v.x); o.y = f2bf(v.y); o.z = f2bf(v.z); o.w = f2bf(v.w);
        ((ushort4*)W1bf)[idx] = o;
    }
}

// ---------------------------------------------------------------------------
// K2: e2[s][b] = V_b + sum_h V[h]*tanh(enc[s,b,:]@W1[h,:] + qb[b][h])
// Flat rows r = s*128+b. Block = 64 rows x 256 h, BK=64, 4 kt.
// 512 thr / 8 waves, all n-split: wave tile 64 rows x 32 h, acc[4][2]=32 VGPR.
// B tile via global_load_lds with pre-swizzled source; A reg-converted fp32->bf16.
// ---------------------------------------------------------------------------
__global__ __launch_bounds__(512, 4) void k_escore(
    const float* __restrict__ enc, const unsigned short* __restrict__ W1bf,
    const float* __restrict__ qb, const float* __restrict__ Vw,
    const float* __restrict__ Vb, float* __restrict__ e2)
{
    __shared__ __align__(16) char As[64 * 128];    // 8KB: 64 rows x 64k bf16, swizzled
    __shared__ __align__(16) char Bs[256 * 128];   // 32KB: 256 cols x 64k bf16, swizzled
    __shared__ float pwave[8][64];

    const int tid = threadIdx.x;
    const int lane = tid & 63, wid = tid >> 6;
    const int lg = lane >> 4, li = lane & 15;
    const int blk = blockIdx.x;
    const size_t row0 = (size_t)blk * 64;

    f32x4 acc[4][2];
    #pragma unroll
    for (int m = 0; m < 4; ++m)
        #pragma unroll
        for (int n = 0; n < 2; ++n)
            acc[m][n] = (f32x4){0.f, 0.f, 0.f, 0.f};

    // B DMA maps: call c covers cols j*8..j*8+7 (j = wid*4+c); lane -> (col, chunk)
    int bcol[4], bchk[4];
    #pragma unroll
    for (int c = 0; c < 4; ++c) {
        const int j = wid * 4 + c;
        bcol[c] = j * 8 + (lane >> 3);
        bchk[c] = (lane & 7) ^ (bcol[c] & 7);
    }
    // A staging map: slot = tid + 512*i -> (row, k16)
    const int swzli = (li & 7) << 4;

    for (int kt = 0; kt < 4; ++kt) {
        __syncthreads();
        // issue B DMA (async; drains at next barrier)
        #pragma unroll
        for (int c = 0; c < 4; ++c)
            glds16(W1bf + (size_t)bcol[c] * HID + kt * 64 + bchk[c] * 8,
                   Bs + (wid * 4 + c) * 1024);
        // stage A (fp32 -> bf16)
        #pragma unroll
        for (int i = 0; i < 2; ++i) {
            const int slot = tid + 512 * i;
            const int row = slot >> 4, k16 = slot & 15;
            float4 v = *(const float4*)(enc + (row0 + row) * HID + kt * 64 + k16 * 4);
            *(uint2*)(As + row * 128 + ((k16 * 8) ^ ((row & 7) << 4))) =
                make_uint2(pack2(v.x, v.y), pack2(v.z, v.w));
        }
        __syncthreads();
        #pragma unroll
        for (int ks = 0; ks < 2; ++ks) {
            short8 a[4];
            #pragma unroll
            for (int m = 0; m < 4; ++m)
                a[m] = *(const short8*)(As + (m * 16 + li) * 128 + ((ks * 64 + lg * 16) ^ swzli));
            #pragma unroll
            for (int n = 0; n < 2; ++n) {
                const int c = wid * 32 + n * 16 + li;
                short8 b = *(const short8*)(Bs + c * 128 + ((ks * 64 + lg * 16) ^ swzli));
                #pragma unroll
                for (int m = 0; m < 4; ++m)
                    acc[m][n] = __builtin_amdgcn_mfma_f32_16x16x32_bf16(a[m], b, acc[m][n], 0, 0, 0);
            }
        }
    }

    // epilogue: per row, p = sum over this wave's 32 h of V[h]*tanh(acc+qb)
    const int bbase = (blk & 1) * 64;
    float vw0 = Vw[wid * 32 + li], vw1 = Vw[wid * 32 + 16 + li];
    #pragma unroll
    for (int m = 0; m < 4; ++m) {
        #pragma unroll
        for (int r = 0; r < 4; ++r) {
            const int lrow = m * 16 + lg * 4 + r;
            const float* qbrow = qb + (size_t)(bbase + lrow) * HID + wid * 32;
            float p = vw0 * fast_tanh(acc[m][0][r] + qbrow[li])
                    + vw1 * fast_tanh(acc[m][1][r] + qbrow[16 + li]);
            p += __shfl_xor(p, 1); p += __shfl_xor(p, 2);
            p += __shfl_xor(p, 4); p += __shfl_xor(p, 8);
            if (li == 0) pwave[wid][lrow] = p;
        }
    }
    __syncthreads();
    if (tid < 64) {
        float s = 0.f;
        #pragma unroll
        for (int w = 0; w < 8; ++w) s += pwave[w][tid];
        e2[(size_t)(blk >> 1) * BB + bbase + tid] = s + Vb[0];
    }
}

// ---------------------------------------------------------------------------
// K3: softmax over s per b; e2 is [s][b]; writes attw [b][s] into d_out
// ---------------------------------------------------------------------------
__global__ __launch_bounds__(256) void k_softmax(
    const float* __restrict__ e2, float* __restrict__ attw)
{
    __shared__ float redm[4];
    __shared__ float reds[4];
    const int b = blockIdx.x, tid = threadIdx.x;
    float v[8];
    float m = -1e30f;
    #pragma unroll
    for (int i = 0; i < 8; ++i) {
        v[i] = e2[(size_t)(tid + i * 256) * BB + b];
        m = fmaxf(m, v[i]);
    }
    #pragma unroll
    for (int off = 1; off < 64; off <<= 1) m = fmaxf(m, __shfl_xor(m, off));
    if ((tid & 63) == 0) redm[tid >> 6] = m;
    __syncthreads();
    m = fmaxf(fmaxf(redm[0], redm[1]), fmaxf(redm[2], redm[3]));
    float sum = 0.f;
    #pragma unroll
    for (int i = 0; i < 8; ++i) { v[i] = __expf(v[i] - m); sum += v[i]; }
    #pragma unroll
    for (int off = 1; off < 64; off <<= 1) sum += __shfl_xor(sum, off);
    if ((tid & 63) == 0) reds[tid >> 6] = sum;
    __syncthreads();
    const float inv = 1.f / (reds[0] + reds[1] + reds[2] + reds[3]);
    float* aw = attw + (size_t)b * SS;
    #pragma unroll
    for (int i = 0; i < 8; ++i) aw[tid + i * 256] = v[i] * inv;
}

// ---------------------------------------------------------------------------
// K4a: partial ctx over an 8-s chunk, reading enc rows CONTIGUOUSLY.
// Thread t owns 16 fixed (b,h4) cells: f4 index q = t + 512*i -> b=q>>6, h4=q&63.
// part[chunk][q] = sum_{s in chunk} attw[b][s] * enc[s][b][h4*4..]
// ---------------------------------------------------------------------------
#define CCH 256
#define CSP 8
__global__ __launch_bounds__(512, 2) void k_ctx_part(
    const float* __restrict__ enc, const float* __restrict__ attw,
    float* __restrict__ part)
{
    __shared__ float aws[CSP * 128];
    const int chunk = blockIdx.x, tid = threadIdx.x;
    const int s0 = chunk * CSP;
    #pragma unroll
    for (int i = 0; i < 2; ++i) {
        const int j = tid + 512 * i;           // j = si*128 + b
        aws[j] = attw[(size_t)(j & 127) * SS + s0 + (j >> 7)];
    }
    __syncthreads();
    f32x4 acc[16];
    #pragma unroll
    for (int i = 0; i < 16; ++i) acc[i] = (f32x4){0.f, 0.f, 0.f, 0.f};
    const int bq = tid >> 6;
    for (int si = 0; si < CSP; ++si) {
        const f32x4* rowp = (const f32x4*)enc + (size_t)(s0 + si) * (BB * HID / 4);
        #pragma unroll
        for (int i = 0; i < 16; ++i)
            acc[i] += rowp[tid + 512 * i] * aws[si * 128 + bq + 8 * i];
    }
    f32x4* p4 = (f32x4*)part + (size_t)chunk * (BB * HID / 4);
    #pragma unroll
    for (int i = 0; i < 16; ++i) p4[tid + 512 * i] = acc[i];
}

// K4b: ctx = sum over chunks of part
__global__ __launch_bounds__(256) void k_ctx_red(
    const float* __restrict__ part, float* __restrict__ ctx)
{
    const int j = blockIdx.x * 256 + threadIdx.x;   // < 8192
    f32x4 s = (f32x4){0.f, 0.f, 0.f, 0.f};
    for (int c = 0; c < CCH; ++c)
        s += ((const f32x4*)part)[(size_t)c * (BB * HID / 4) + j];
    ((f32x4*)ctx)[j] = s;
}

// ---------------------------------------------------------------------------
// K5: LSTM step (fp32 exact). One block per b. Also emits h_new in bf16.
// ---------------------------------------------------------------------------
__global__ __launch_bounds__(256) void k_lstm(
    const float* __restrict__ ctx, const int* __restrict__ x,
    const float* __restrict__ emb_table, const float* __restrict__ hidden,
    const float* __restrict__ cell,
    const float* __restrict__ W_ih, const float* __restrict__ W_hh,
    const float* __restrict__ b_ih, const float* __restrict__ b_hh,
    float* __restrict__ out_h, float* __restrict__ out_c,
    unsigned short* __restrict__ hbf)
{
    __shared__ float rin[768];     // [ctx | emb | h0]
    __shared__ float gates[1024];
    const int b = blockIdx.x, tid = threadIdx.x;
    rin[tid]       = ctx[b * HID + tid];
    rin[256 + tid] = emb_table[(size_t)x[b] * EMB + tid];
    rin[512 + tid] = hidden[b * HID + tid];
    __syncthreads();
    #pragma unroll
    for (int jj = 0; jj < 4; ++jj) {
        const int j = jj * 256 + tid;
        float acc = b_ih[j] + b_hh[j];
        const float4* wi = (const float4*)(W_ih + (size_t)j * 512);
        #pragma unroll 4
        for (int k4 = 0; k4 < 128; ++k4) {
            float4 w = wi[k4];
            acc += w.x*rin[k4*4] + w.y*rin[k4*4+1] + w.z*rin[k4*4+2] + w.w*rin[k4*4+3];
        }
        const float4* wh = (const float4*)(W_hh + (size_t)j * 256);
        #pragma unroll 4
        for (int k4 = 0; k4 < 64; ++k4) {
            float4 w = wh[k4];
            acc += w.x*rin[512+k4*4] + w.y*rin[512+k4*4+1] + w.z*rin[512+k4*4+2] + w.w*rin[512+k4*4+3];
        }
        gates[j] = acc;
    }
    __syncthreads();
    const float ig = gates[tid], fg = gates[256 + tid];
    const float gg = gates[512 + tid], og = gates[768 + tid];
    const float c0 = cell[b * HID + tid];
    const float si = 1.f / (1.f + __expf(-ig));
    const float sf = 1.f / (1.f + __expf(-fg));
    const float so = 1.f / (1.f + __expf(-og));
    const float cn = sf * c0 + si * tanhf(gg);
    const float hn = so * tanhf(cn);
    out_c[b * HID + tid] = cn;
    out_h[b * HID + tid] = hn;
    hbf[b * HID + tid] = f2bf(hn);
}

// ---------------------------------------------------------------------------
// K6: pred[b][v] = h_new[b]@fc_w[v] + fc_b[v]. Tile 128x128, BK=64, 4 kt.
// 512 thr / 8 waves (2m x 4n): wave tile 64 rows x 32 cols, acc[4][2].
// A (bf16 h_new) via global_load_lds; B (fp32 fc_w) reg-converted.
// ---------------------------------------------------------------------------
__global__ __launch_bounds__(512, 4) void k_fc(
    const unsigned short* __restrict__ hbf, const float* __restrict__ fcw,
    const float* __restrict__ fcb, float* __restrict__ pred)
{
    __shared__ __align__(16) char As[128 * 128];   // 16KB
    __shared__ __align__(16) char Bs[128 * 128];   // 16KB
    const int vbase = blockIdx.x * 128;
    const int tid = threadIdx.x;
    const int lane = tid & 63, wid = tid >> 6;
    const int wm = wid >> 2, wn = wid & 3;
    const int lg = lane >> 4, li = lane & 15;
    const int swzli = (li & 7) << 4;

    f32x4 acc[4][2];
    #pragma unroll
    for (int m = 0; m < 4; ++m)
        #pragma unroll
        for (int n = 0; n < 2; ++n)
            acc[m][n] = (f32x4){0.f, 0.f, 0.f, 0.f};

    int arow[2], achk[2];
    #pragma unroll
    for (int c = 0; c < 2; ++c) {
        const int j = wid * 2 + c;
        arow[c] = j * 8 + (lane >> 3);
        achk[c] = (lane & 7) ^ (arow[c] & 7);
    }

    for (int kt = 0; kt < 4; ++kt) {
        __syncthreads();
        #pragma unroll
        for (int c = 0; c < 2; ++c)
            glds16(hbf + (size_t)arow[c] * HID + kt * 64 + achk[c] * 8,
                   As + (wid * 2 + c) * 1024);
        #pragma unroll
        for (int i = 0; i < 4; ++i) {
            const int slot = tid + 512 * i;
            const int brow = slot >> 4, k16 = slot & 15;
            const int v = min(vbase + brow, VOCAB - 1);
            float4 w = *(const float4*)(fcw + (size_t)v * HID + kt * 64 + k16 * 4);
            *(uint2*)(Bs + brow * 128 + ((k16 * 8) ^ ((brow & 7) << 4))) =
                make_uint2(pack2(w.x, w.y), pack2(w.z, w.w));
        }
        __syncthreads();
        #pragma unroll
        for (int ks = 0; ks < 2; ++ks) {
            short8 a[4];
            #pragma unroll
            for (int m = 0; m < 4; ++m) {
                const int r = wm * 64 + m * 16 + li;
                a[m] = *(const short8*)(As + r * 128 + ((ks * 64 + lg * 16) ^ swzli));
            }
            #pragma unroll
            for (int n = 0; n < 2; ++n) {
                const int c = wn * 32 + n * 16 + li;
                short8 b = *(const short8*)(Bs + c * 128 + ((ks * 64 + lg * 16) ^ swzli));
                #pragma unroll
                for (int m = 0; m < 4; ++m)
                    acc[m][n] = __builtin_amdgcn_mfma_f32_16x16x32_bf16(a[m], b, acc[m][n], 0, 0, 0);
            }
        }
    }

    #pragma unroll
    for (int m = 0; m < 4; ++m)
        #pragma unroll
        for (int r = 0; r < 4; ++r) {
            const int row = wm * 64 + m * 16 + lg * 4 + r;
            #pragma unroll
            for (int n = 0; n < 2; ++n) {
                const int col = vbase + wn * 32 + n * 16 + li;
                if (col < VOCAB)
                    pred[(size_t)row * VOCAB + col] = acc[m][n][r] + fcb[col];
            }
        }
}

// ---------------------------------------------------------------------------
extern "C" void kernel_launch(void* const* d_in, const int* in_sizes, int n_in,
                              void* d_out, int out_size, void* d_ws, size_t ws_size,
                              hipStream_t stream)
{
    const int*   x      = (const int*)  d_in[0];
    const float* enc    = (const float*)d_in[1];
    const float* hidden = (const float*)d_in[2];
    const float* cell   = (const float*)d_in[3];
    const float* emb    = (const float*)d_in[4];
    const float* W_ih   = (const float*)d_in[5];
    const float* W_hh   = (const float*)d_in[6];
    const float* b_ih   = (const float*)d_in[7];
    const float* b_hh   = (const float*)d_in[8];
    const float* fc_w   = (const float*)d_in[9];
    const float* fc_b   = (const float*)d_in[10];
    const float* W1_w   = (const float*)d_in[11];
    const float* W1_b   = (const float*)d_in[12];
    const float* W2_w   = (const float*)d_in[13];
    const float* W2_b   = (const float*)d_in[14];
    const float* V_w    = (const float*)d_in[15];
    const float* V_b    = (const float*)d_in[16];

    float* out   = (float*)d_out;
    float* pred  = out;                                   // [128][50257]
    float* out_h = out + (size_t)BB * VOCAB;              // [128][256]
    float* out_c = out_h + BB * HID;                      // [128][256]
    float* attw  = out_c + BB * HID;                      // [128][2048]

    char* ws = (char*)d_ws;
    unsigned short* W1bf = (unsigned short*)ws;           // 128 KiB
    float* qb   = (float*)(ws + 131072);                  // 128 KiB
    float* e2   = (float*)(ws + 262144);                  // 1 MiB [s][b]
    float* ctx  = (float*)(ws + 1310720);                 // 128 KiB
    unsigned short* hbf = (unsigned short*)(ws + 1441792);// 64 KiB
    float* part = (float*)(ws + 2097152);                 // 8 MiB

    k_prep    <<<dim3(192),  dim3(256), 0, stream>>>(hidden, W2_w, W1_b, W2_b, W1_w, W1bf, qb);
    k_escore  <<<dim3(4096), dim3(512), 0, stream>>>(enc, W1bf, qb, V_w, V_b, e2);
    k_softmax <<<dim3(BB),   dim3(256), 0, stream>>>(e2, attw);
    k_ctx_part<<<dim3(CCH),  dim3(512), 0, stream>>>(enc, attw, part);
    k_ctx_red <<<dim3(32),   dim3(256), 0, stream>>>(part, ctx);
    k_lstm    <<<dim3(BB),   dim3(256), 0, stream>>>(ctx, x, emb, hidden, cell,
                                                     W_ih, W_hh, b_ih, b_hh, out_h, out_c, hbf);
    k_fc      <<<dim3((VOCAB + 127)/128), dim3(512), 0, stream>>>(hbf, fc_w, fc_b, pred);
}